// Round 1
// baseline (1072.861 us; speedup 1.0000x reference)
//
#include <hip/hip_runtime.h>

// ============================================================================
// GNN_22170621182157: fused attention-ish block on MI355X (gfx950).
//
// Math reduction (softmax row-shift invariance):
//   adj[n,m] = q_n . k_m ;  q = F Wq + bq, k = F Wk + bk
//            = f_n^T (Wq Wk^T) f_m + [row-const terms] + (Wk bq . f_m)
//   -> softmax(adj) == softmax( S F^T + 1*c^T ),
//      S = F Mt^T,  Mt = Wk Wq^T,  c = F (Wk bq)
//   out = P (F Wu) + bu   (since rows of P sum to 1, bias exact in epilogue)
//
// Precision: split-bf16 (hi/lo, 3 MFMA passes) for Mt, S, adj — logit error
// ~3e-4 vs bf16-direct ~0.14 (would fail 0.11 threshold). Plain bf16 for
// v = F Wu and out = P v.
// ============================================================================

typedef unsigned short u16;
typedef unsigned int   u32;
typedef __bf16 bf16x8 __attribute__((ext_vector_type(8)));
typedef float  f32x4  __attribute__((ext_vector_type(4)));
typedef u32    u32x4  __attribute__((ext_vector_type(4)));
typedef u16    u16x4  __attribute__((ext_vector_type(4)));

__device__ __forceinline__ u16 f2bf(float f) {
    u32 u = __builtin_bit_cast(u32, f);
    u += 0x7fffu + ((u >> 16) & 1u);   // RNE
    return (u16)(u >> 16);
}
__device__ __forceinline__ float bf2f(u16 h) {
    u32 u = ((u32)h) << 16;
    return __builtin_bit_cast(float, u);
}

// ---------------------------------------------------------------------------
// Pre-pass: fp32 -> (hi, lo) bf16 split.  x ~= hi + lo to ~2^-18 rel.
// ---------------------------------------------------------------------------
__global__ __launch_bounds__(256) void split_k(const float* __restrict__ x,
                                               u16* __restrict__ hi,
                                               u16* __restrict__ lo, long n) {
    long i = (long)blockIdx.x * 256 + threadIdx.x;
    if (i < n) {
        float v = x[i];
        u16 h = f2bf(v);
        hi[i] = h;
        lo[i] = f2bf(v - bf2f(h));
    }
}

// Wu [2048][1024] fp32 -> WuT [1024][2048] bf16 (plain)
__global__ __launch_bounds__(256) void wut_k(const float* __restrict__ Wu,
                                             u16* __restrict__ WuT) {
    long i = (long)blockIdx.x * 256 + threadIdx.x;  // over 2048*1024
    int r  = (int)(i >> 10);
    int cc = (int)(i & 1023);
    WuT[(long)cc * 2048 + r] = f2bf(Wu[i]);
}

// y[row] = A[row,:] . x   (fp32, exact path for the logit column-bias c)
__global__ __launch_bounds__(256) void gemv_k(const float* __restrict__ A,
                                              const float* __restrict__ x,
                                              float* __restrict__ y, int ncols) {
    const long row = blockIdx.x;
    const float* ar = A + row * (long)ncols;
    float s = 0.f;
    for (int i = threadIdx.x; i < ncols; i += 256) s += ar[i] * x[i];
    #pragma unroll
    for (int off = 32; off >= 1; off >>= 1) s += __shfl_down(s, off);
    __shared__ float red[4];
    if ((threadIdx.x & 63) == 0) red[threadIdx.x >> 6] = s;
    __syncthreads();
    if (threadIdx.x == 0) y[row] = red[0] + red[1] + red[2] + red[3];
}

// ---------------------------------------------------------------------------
// Main tiled GEMM: C[M,N] = A[M,K] @ Bt[N,K]^T   (both operands row-major,
// K contiguous; B is pre-transposed).  128x128 block tile, BK=32, 4 waves
// in 2x2, each wave 4x4 tiles of v_mfma_f32_16x16x32_bf16.
// SPLIT: 3-pass hi/lo emulation (Ah*Bh + Ah*Bl + Al*Bh).
// EPI: 0 = fp32 C;  1 = split bf16 (Ch,Cl);  2 = bf16 transposed (vT, with
//      batch decompose of flat M=9216);  3 = fp32 + bias[col].
// Verified gfx950 layouts: A-frag lane holds A[m=lane&15][k=(lane>>4)*8+j];
// B-frag lane holds B[k=(lane>>4)*8+j][n=lane&15]; C/D col=lane&15,
// row=(lane>>4)*4+reg.
// ---------------------------------------------------------------------------
template <int SPLIT, int EPI>
__global__ __launch_bounds__(256, 2) void gemm_tile(
    const u16* __restrict__ Ah, const u16* __restrict__ Al,
    const u16* __restrict__ Bh, const u16* __restrict__ Bl,
    float* __restrict__ Cf, u16* __restrict__ Ch, u16* __restrict__ Cl,
    const float* __restrict__ bias,
    int M, int N, int K, long strA, long strB, long strC) {
    (void)M;
    constexpr int LDT = 40;  // 32 + 8 pad (rows stay 16B aligned, kills conflicts)
    __shared__ u16 shA[SPLIT ? 2 : 1][128 * LDT];
    __shared__ u16 shB[SPLIT ? 2 : 1][128 * LDT];

    const int tid  = threadIdx.x;
    const int lane = tid & 63;
    const int wv   = tid >> 6;
    const int wm   = wv >> 1, wn = wv & 1;
    const int l16  = lane & 15, kq = lane >> 4;
    const int z    = blockIdx.z;
    const long rowBase = (long)blockIdx.y * 128;
    const long colBase = (long)blockIdx.x * 128;

    const u16* pAh = Ah + (long)z * strA;
    const u16* pBh = Bh + (long)z * strB;
    const u16* pAl = nullptr;
    const u16* pBl = nullptr;
    if constexpr (SPLIT) { pAl = Al + (long)z * strA; pBl = Bl + (long)z * strB; }

    // staging: idx = c*256+tid -> row = idx>>2, col8 = (idx&3)*8 (16B chunks)
    const int r0 = tid >> 2;
    const int c0 = (tid & 3) * 8;
    const int r1 = r0 + 64;
    const long aoff0 = (rowBase + r0) * (long)K + c0;
    const long aoff1 = (rowBase + r1) * (long)K + c0;
    const long boff0 = (colBase + r0) * (long)K + c0;
    const long boff1 = (colBase + r1) * (long)K + c0;
    const int sidx0 = r0 * LDT + c0;
    const int sidx1 = r1 * LDT + c0;

    const f32x4 vzero = {0.f, 0.f, 0.f, 0.f};
    f32x4 acc[4][4];
    #pragma unroll
    for (int i = 0; i < 4; ++i)
        #pragma unroll
        for (int j = 0; j < 4; ++j) acc[i][j] = vzero;

    const int nk = K >> 5;
    for (int kt = 0; kt < nk; ++kt) {
        const long ko = (long)kt * 32;
        u32x4 stA[SPLIT ? 4 : 2], stB[SPLIT ? 4 : 2];
        stA[0] = *(const u32x4*)(pAh + aoff0 + ko);
        stA[1] = *(const u32x4*)(pAh + aoff1 + ko);
        stB[0] = *(const u32x4*)(pBh + boff0 + ko);
        stB[1] = *(const u32x4*)(pBh + boff1 + ko);
        if constexpr (SPLIT) {
            stA[2] = *(const u32x4*)(pAl + aoff0 + ko);
            stA[3] = *(const u32x4*)(pAl + aoff1 + ko);
            stB[2] = *(const u32x4*)(pBl + boff0 + ko);
            stB[3] = *(const u32x4*)(pBl + boff1 + ko);
        }
        __syncthreads();  // previous iteration's LDS reads complete
        *(u32x4*)&shA[0][sidx0] = stA[0];
        *(u32x4*)&shA[0][sidx1] = stA[1];
        *(u32x4*)&shB[0][sidx0] = stB[0];
        *(u32x4*)&shB[0][sidx1] = stB[1];
        if constexpr (SPLIT) {
            *(u32x4*)&shA[1][sidx0] = stA[2];
            *(u32x4*)&shA[1][sidx1] = stA[3];
            *(u32x4*)&shB[1][sidx0] = stB[2];
            *(u32x4*)&shB[1][sidx1] = stB[3];
        }
        __syncthreads();

        bf16x8 ah[4], al[4];
        #pragma unroll
        for (int i = 0; i < 4; ++i) {
            const int off = (wm * 64 + i * 16 + l16) * LDT + kq * 8;
            ah[i] = __builtin_bit_cast(bf16x8, *(const u32x4*)&shA[0][off]);
            if constexpr (SPLIT)
                al[i] = __builtin_bit_cast(bf16x8, *(const u32x4*)&shA[1][off]);
        }
        #pragma unroll
        for (int j = 0; j < 4; ++j) {
            const int off = (wn * 64 + j * 16 + l16) * LDT + kq * 8;
            bf16x8 bh = __builtin_bit_cast(bf16x8, *(const u32x4*)&shB[0][off]);
            #pragma unroll
            for (int i = 0; i < 4; ++i)
                acc[i][j] = __builtin_amdgcn_mfma_f32_16x16x32_bf16(ah[i], bh, acc[i][j], 0, 0, 0);
            if constexpr (SPLIT) {
                bf16x8 bl = __builtin_bit_cast(bf16x8, *(const u32x4*)&shB[1][off]);
                #pragma unroll
                for (int i = 0; i < 4; ++i) {
                    acc[i][j] = __builtin_amdgcn_mfma_f32_16x16x32_bf16(ah[i], bl, acc[i][j], 0, 0, 0);
                    acc[i][j] = __builtin_amdgcn_mfma_f32_16x16x32_bf16(al[i], bh, acc[i][j], 0, 0, 0);
                }
            }
        }
    }

    // epilogue
    #pragma unroll
    for (int i = 0; i < 4; ++i) {
        const long gr0 = rowBase + wm * 64 + i * 16 + kq * 4;
        #pragma unroll
        for (int j = 0; j < 4; ++j) {
            const long gc = colBase + wn * 64 + j * 16 + l16;
            f32x4 a = acc[i][j];
            if constexpr (EPI == 0) {
                float* C = Cf + (long)z * strC;
                #pragma unroll
                for (int r = 0; r < 4; ++r) C[(gr0 + r) * (long)N + gc] = a[r];
            } else if constexpr (EPI == 1) {
                #pragma unroll
                for (int r = 0; r < 4; ++r) {
                    const long o = (gr0 + r) * (long)N + gc;
                    u16 h = f2bf(a[r]);
                    Ch[o] = h;
                    Cl[o] = f2bf(a[r] - bf2f(h));
                }
            } else if constexpr (EPI == 2) {
                // flat M rows -> (batch, n); write vT[b][col][n..n+3]
                const int b  = (int)(gr0 / 2304);
                const int n0 = (int)(gr0 - (long)b * 2304);
                u16x4 o4;
                #pragma unroll
                for (int r = 0; r < 4; ++r) o4[r] = f2bf(a[r]);
                *(u16x4*)&Ch[(long)b * (1024L * 2304) + gc * 2304 + n0] = o4;
            } else {
                float* C = Cf + (long)z * strC;
                const float bv = bias[gc];
                #pragma unroll
                for (int r = 0; r < 4; ++r) C[(gr0 + r) * (long)N + gc] = a[r] + bv;
            }
        }
    }
}

// ---------------------------------------------------------------------------
// Row softmax over 2304 cols with per-column bias c[m]; fp32 in, bf16 out.
// One block (256 thr) per row; 9 elements/thread.
// ---------------------------------------------------------------------------
__global__ __launch_bounds__(256) void softmax_k(const float* __restrict__ adj,
                                                 const float* __restrict__ c,
                                                 u16* __restrict__ P) {
    const int n = 2304;
    const int row = blockIdx.x, b = blockIdx.y;
    const int tid = threadIdx.x;
    const float* ar = adj + ((long)b * n + row) * (long)n;
    const float* cb = c + (long)b * n;
    u16* pr = P + ((long)b * n + row) * (long)n;

    float v[9];
    float mx = -3.0e38f;
    #pragma unroll
    for (int t = 0; t < 9; ++t) {
        const int i = t * 256 + tid;
        const float x = ar[i] + cb[i];
        v[t] = x;
        mx = fmaxf(mx, x);
    }
    #pragma unroll
    for (int off = 32; off >= 1; off >>= 1) mx = fmaxf(mx, __shfl_down(mx, off));
    __shared__ float red[4];
    if ((tid & 63) == 0) red[tid >> 6] = mx;
    __syncthreads();
    mx = fmaxf(fmaxf(red[0], red[1]), fmaxf(red[2], red[3]));

    float s = 0.f;
    #pragma unroll
    for (int t = 0; t < 9; ++t) {
        const float e = __expf(v[t] - mx);
        v[t] = e;
        s += e;
    }
    #pragma unroll
    for (int off = 32; off >= 1; off >>= 1) s += __shfl_down(s, off);
    __shared__ float red2[4];
    if ((tid & 63) == 0) red2[tid >> 6] = s;
    __syncthreads();
    s = red2[0] + red2[1] + red2[2] + red2[3];
    const float inv = 1.0f / s;
    #pragma unroll
    for (int t = 0; t < 9; ++t) pr[t * 256 + tid] = f2bf(v[t] * inv);
}

// ---------------------------------------------------------------------------
// Host launch
// ---------------------------------------------------------------------------
extern "C" void kernel_launch(void* const* d_in, const int* in_sizes, int n_in,
                              void* d_out, int out_size, void* d_ws, size_t ws_size,
                              hipStream_t stream) {
    (void)in_sizes; (void)n_in; (void)out_size; (void)ws_size;
    const float* F  = (const float*)d_in[0];  // [4*2304, 2048]
    const float* Wq = (const float*)d_in[1];  // [2048,2048]
    const float* bq = (const float*)d_in[2];  // [2048]
    const float* Wk = (const float*)d_in[3];  // [2048,2048]
    // d_in[4] (bk) drops out: row-constant under softmax.
    const float* Wu = (const float*)d_in[5];  // [2048,1024]
    const float* bu = (const float*)d_in[6];  // [1024]
    float* out = (float*)d_out;               // [4*2304, 1024]

    char* ws = (char*)d_ws;
    // Workspace layout (bytes); Wq/Wk splits alias adj (dead before adj
    // written), Mt aliases P (dead before P written).  Total ~287.5 MiB.
    const long o_Fhi = 0L;
    const long o_Flo = 37748736L;
    const long o_Shi = 75497472L;
    const long o_Slo = 113246208L;
    const long o_adj = 150994944L;              // 84,934,656 B
    const long o_Wqh = o_adj;
    const long o_Wql = o_adj + 8388608L;
    const long o_Wkh = o_adj + 16777216L;
    const long o_Wkl = o_adj + 25165824L;
    const long o_P   = 235929600L;              // 42,467,328 B
    const long o_Mth = o_P;
    const long o_Mtl = o_P + 8388608L;
    const long o_WuT = 278396928L;
    const long o_vT  = 282591232L;
    const long o_u   = 301465600L;
    const long o_c   = 301473792L;

    u16* Fhi = (u16*)(ws + o_Fhi);   u16* Flo = (u16*)(ws + o_Flo);
    u16* Shi = (u16*)(ws + o_Shi);   u16* Slo = (u16*)(ws + o_Slo);
    float* adj = (float*)(ws + o_adj);
    u16* Wqh = (u16*)(ws + o_Wqh);   u16* Wql = (u16*)(ws + o_Wql);
    u16* Wkh = (u16*)(ws + o_Wkh);   u16* Wkl = (u16*)(ws + o_Wkl);
    u16* P   = (u16*)(ws + o_P);
    u16* Mth = (u16*)(ws + o_Mth);   u16* Mtl = (u16*)(ws + o_Mtl);
    u16* WuT = (u16*)(ws + o_WuT);
    u16* vT  = (u16*)(ws + o_vT);
    float* u = (float*)(ws + o_u);
    float* c = (float*)(ws + o_c);

    // --- pre-passes ---
    split_k<<<73728, 256, 0, stream>>>(F, Fhi, Flo, 18874368L);
    split_k<<<16384, 256, 0, stream>>>(Wq, Wqh, Wql, 4194304L);
    split_k<<<16384, 256, 0, stream>>>(Wk, Wkh, Wkl, 4194304L);
    wut_k<<<8192, 256, 0, stream>>>(Wu, WuT);
    gemv_k<<<2048, 256, 0, stream>>>(Wk, bq, u, 2048);   // u = Wk bq
    gemv_k<<<9216, 256, 0, stream>>>(F, u, c, 2048);     // c = F u

    // --- Mt = Wk @ Wq^T  [2048 x 2048], split in/out ---
    gemm_tile<1, 1><<<dim3(16, 16, 1), 256, 0, stream>>>(
        Wkh, Wkl, Wqh, Wql, nullptr, Mth, Mtl, nullptr,
        2048, 2048, 2048, 0L, 0L, 0L);

    // --- S = F @ Mt^T  [9216 x 2048], split in/out ---
    gemm_tile<1, 1><<<dim3(16, 72, 1), 256, 0, stream>>>(
        Fhi, Flo, Mth, Mtl, nullptr, Shi, Slo, nullptr,
        9216, 2048, 2048, 0L, 0L, 0L);

    // --- v = F @ Wu (plain bf16), written transposed as vT[b][1024][2304] ---
    gemm_tile<0, 2><<<dim3(8, 72, 1), 256, 0, stream>>>(
        Fhi, nullptr, WuT, nullptr, nullptr, vT, nullptr, nullptr,
        9216, 1024, 2048, 0L, 0L, 0L);

    // --- adj = S @ F^T per batch, fp32 out ---
    gemm_tile<1, 0><<<dim3(18, 18, 4), 256, 0, stream>>>(
        Shi, Slo, Fhi, Flo, adj, nullptr, nullptr, nullptr,
        2304, 2304, 2048, 2304L * 2048, 2304L * 2048, 2304L * 2304);

    // --- P = softmax(adj + c) per row, bf16 out ---
    softmax_k<<<dim3(2304, 4, 1), 256, 0, stream>>>(adj, c, P);

    // --- out = P @ v + bu, fp32 to d_out ---
    gemm_tile<0, 3><<<dim3(8, 18, 4), 256, 0, stream>>>(
        P, nullptr, vT, nullptr, out, nullptr, nullptr, bu,
        2304, 1024, 2304, 2304L * 2304, 1024L * 2304, 2304L * 1024);
}

// Round 3
// 887.745 us; speedup vs baseline: 1.2085x; 1.2085x over previous
//
#include <hip/hip_runtime.h>

// ============================================================================
// GNN_22170621182157 R3: logit chain (Mt, S, adj) in base-256 2-digit int8
// fixed-point, FULL 4-pass product (hh, a1b0+a0b1, a0b0) via a two-phase
// K-loop (phase 1: hh+cross in 2 i32 acc sets -> collapse to fp32; phase 2:
// ll re-streaming lo planes into 1 reused i32 set).  v/P/out chain in fp16.
//
// R2 post-mortem: dropped a0b0 term contributes logit sigma ~0.015 (base-
// independent floor ~8e-3 for any 3-pass scheme) -> 4th pass is mandatory.
//
// Math reduction (softmax row-shift invariance):
//   softmax(adj) == softmax( S F^T + 1*c^T ),  S = F Mt^T,  Mt = Wk Wq^T,
//   c = F (Wk bq);  out = P (F Wu) + bu.
//
// Fixed-point: x ~ r/s, r 16-bit = a1*256 + a0 (a1,a0 in i8; a1=(r+128)>>8).
//   s_F = s_S = 5440 (max|F|,|S| ~ 5.6 -> r <= 30464 < 32600 clamp)
//   s_W = s_Mt = 261120 (max|W|,|Mt| ~ 0.125)
//   comb = 65536*acc(a1b1) + 256*acc(a1b0+a0b1) + acc(a0b0); val = comb/(sA*sB)
//   err budget: dMt 1.9e-6 -> dS 1.13e-4 -> sigma_adj 5.6e-3 -> out ~0.037.
// ============================================================================

typedef unsigned short u16;
typedef unsigned int   u32;
typedef signed char    i8;
typedef _Float16 f16;
typedef f16    f16x8 __attribute__((ext_vector_type(8)));
typedef float  f32x4 __attribute__((ext_vector_type(4)));
typedef int    i32x4 __attribute__((ext_vector_type(4)));
typedef u32    u32x4 __attribute__((ext_vector_type(4)));
typedef u16    u16x4 __attribute__((ext_vector_type(4)));

// ---------------------------------------------------------------------------
// Tile swizzle (triton GROUP_M style) for L2 locality.
// ---------------------------------------------------------------------------
__device__ __forceinline__ void tile_swizzle(int& tx, int& ty) {
    const int gx = gridDim.x, gy = gridDim.y;
    const int lin = blockIdx.y * gx + blockIdx.x;
    const int G = 4;
    const int gid = lin / (G * gx);
    const int g0 = gid * G;
    const int gh = min(G, gy - g0);
    const int rem = lin - gid * (G * gx);
    ty = g0 + rem % gh;
    tx = rem / gh;
}

__device__ __forceinline__ void digits256(float v, float s, i8& d1, i8& d0) {
    float f = fminf(fmaxf(v * s, -32600.0f), 32600.0f);
    int r = __float2int_rn(f);
    int a1 = (r + 128) >> 8;          // a1 in [-128,127]
    int a0 = r - (a1 << 8);           // a0 in [-128,127]
    d1 = (i8)a1;
    d0 = (i8)a0;
}

// ---------------------------------------------------------------------------
// Pre-passes
// ---------------------------------------------------------------------------
// F fp32 -> fp16 + two i8 digit planes at scale 5440
__global__ __launch_bounds__(256) void quantF_k(const float* __restrict__ x,
                                                u16* __restrict__ xf16,
                                                i8* __restrict__ hi,
                                                i8* __restrict__ lo, long n) {
    long i = (long)blockIdx.x * 256 + threadIdx.x;
    if (i < n) {
        float v = x[i];
        xf16[i] = __builtin_bit_cast(u16, (f16)v);
        i8 d1, d0;
        digits256(v, 5440.0f, d1, d0);
        hi[i] = d1;
        lo[i] = d0;
    }
}

// W fp32 -> two i8 digit planes at scale 261120
__global__ __launch_bounds__(256) void quantW_k(const float* __restrict__ x,
                                                i8* __restrict__ hi,
                                                i8* __restrict__ lo, long n) {
    long i = (long)blockIdx.x * 256 + threadIdx.x;
    if (i < n) {
        i8 d1, d0;
        digits256(x[i], 261120.0f, d1, d0);
        hi[i] = d1;
        lo[i] = d0;
    }
}

// Wu [2048][1024] fp32 -> WuT [1024][2048] fp16
__global__ __launch_bounds__(256) void wut_k(const float* __restrict__ Wu,
                                             u16* __restrict__ WuT) {
    long i = (long)blockIdx.x * 256 + threadIdx.x;
    int r  = (int)(i >> 10);
    int cc = (int)(i & 1023);
    WuT[(long)cc * 2048 + r] = __builtin_bit_cast(u16, (f16)Wu[i]);
}

// y[row] = A[row,:] . x   (fp32, exact path for logit column-bias c)
__global__ __launch_bounds__(256) void gemv_k(const float* __restrict__ A,
                                              const float* __restrict__ x,
                                              float* __restrict__ y, int ncols) {
    const long row = blockIdx.x;
    const float* ar = A + row * (long)ncols;
    float s = 0.f;
    for (int i = threadIdx.x; i < ncols; i += 256) s += ar[i] * x[i];
    #pragma unroll
    for (int off = 32; off >= 1; off >>= 1) s += __shfl_down(s, off);
    __shared__ float red[4];
    if ((threadIdx.x & 63) == 0) red[threadIdx.x >> 6] = s;
    __syncthreads();
    if (threadIdx.x == 0) y[row] = red[0] + red[1] + red[2] + red[3];
}

// ---------------------------------------------------------------------------
// i8 2-digit 4-pass GEMM: C[M,N] = A[M,K] @ Bt[N,K]^T, K%64==0.
// 128x128 tile, BK=64, 4 waves 2x2, each wave 4x4 of mfma_i32_16x16x64_i8.
// Phase 1: hh + cross (2 i32 sets) -> fp32 part. Phase 2: ll (1 i32 set).
// EPI 0: re-quantize to base-256 digit planes.  EPI 1: fp32 out.
// ---------------------------------------------------------------------------
template <int EPI>
__global__ __launch_bounds__(256, 2) void gemm_i8(
    const i8* __restrict__ Ah, const i8* __restrict__ Al,
    const i8* __restrict__ Bh, const i8* __restrict__ Bl,
    i8* __restrict__ Qh, i8* __restrict__ Ql, float* __restrict__ Cf,
    float oscale, int N, int K, long strA, long strB, long strC) {
    constexpr int LDT = 80;  // 64 + 16 pad bytes
    __shared__ i8 shA[2][128 * LDT];
    __shared__ i8 shB[2][128 * LDT];

    const int tid  = threadIdx.x;
    const int lane = tid & 63;
    const int wv   = tid >> 6;
    const int wm   = wv >> 1, wn = wv & 1;
    const int l16  = lane & 15, kq = lane >> 4;
    const int z    = blockIdx.z;
    int tx, ty;
    tile_swizzle(tx, ty);
    const long rowBase = (long)ty * 128;
    const long colBase = (long)tx * 128;

    const i8* pAh = Ah + (long)z * strA;
    const i8* pAl = Al + (long)z * strA;
    const i8* pBh = Bh + (long)z * strB;
    const i8* pBl = Bl + (long)z * strB;

    const int r0 = tid >> 2;
    const int c0 = (tid & 3) * 16;
    const int r1 = r0 + 64;
    const long aoff0 = (rowBase + r0) * (long)K + c0;
    const long aoff1 = (rowBase + r1) * (long)K + c0;
    const long boff0 = (colBase + r0) * (long)K + c0;
    const long boff1 = (colBase + r1) * (long)K + c0;
    const int sidx0 = r0 * LDT + c0;
    const int sidx1 = r1 * LDT + c0;

    const i32x4 izero = {0, 0, 0, 0};
    const int nk = K >> 6;

    // ---- phase 1: hh + cross ----
    i32x4 achh[4][4], acx[4][4];
    #pragma unroll
    for (int i = 0; i < 4; ++i)
        #pragma unroll
        for (int j = 0; j < 4; ++j) { achh[i][j] = izero; acx[i][j] = izero; }

    for (int kt = 0; kt < nk; ++kt) {
        const long ko = (long)kt * 64;
        u32x4 sA0 = *(const u32x4*)(pAh + aoff0 + ko);
        u32x4 sA1 = *(const u32x4*)(pAh + aoff1 + ko);
        u32x4 sA2 = *(const u32x4*)(pAl + aoff0 + ko);
        u32x4 sA3 = *(const u32x4*)(pAl + aoff1 + ko);
        u32x4 sB0 = *(const u32x4*)(pBh + boff0 + ko);
        u32x4 sB1 = *(const u32x4*)(pBh + boff1 + ko);
        u32x4 sB2 = *(const u32x4*)(pBl + boff0 + ko);
        u32x4 sB3 = *(const u32x4*)(pBl + boff1 + ko);
        __syncthreads();  // prior iteration's LDS reads complete
        *(u32x4*)&shA[0][sidx0] = sA0;
        *(u32x4*)&shA[0][sidx1] = sA1;
        *(u32x4*)&shA[1][sidx0] = sA2;
        *(u32x4*)&shA[1][sidx1] = sA3;
        *(u32x4*)&shB[0][sidx0] = sB0;
        *(u32x4*)&shB[0][sidx1] = sB1;
        *(u32x4*)&shB[1][sidx0] = sB2;
        *(u32x4*)&shB[1][sidx1] = sB3;
        __syncthreads();

        i32x4 fah[4], fal[4];
        #pragma unroll
        for (int i = 0; i < 4; ++i) {
            const int off = (wm * 64 + i * 16 + l16) * LDT + kq * 16;
            fah[i] = *(const i32x4*)&shA[0][off];
            fal[i] = *(const i32x4*)&shA[1][off];
        }
        #pragma unroll
        for (int j = 0; j < 4; ++j) {
            const int off = (wn * 64 + j * 16 + l16) * LDT + kq * 16;
            i32x4 fbh = *(const i32x4*)&shB[0][off];
            i32x4 fbl = *(const i32x4*)&shB[1][off];
            #pragma unroll
            for (int i = 0; i < 4; ++i) {
                achh[i][j] = __builtin_amdgcn_mfma_i32_16x16x64_i8(fah[i], fbh, achh[i][j], 0, 0, 0);
                acx[i][j]  = __builtin_amdgcn_mfma_i32_16x16x64_i8(fah[i], fbl, acx[i][j], 0, 0, 0);
                acx[i][j]  = __builtin_amdgcn_mfma_i32_16x16x64_i8(fal[i], fbh, acx[i][j], 0, 0, 0);
            }
        }
    }

    // collapse: hh,cross counts < 2^24-ish -> fp32 combine near-exact
    f32x4 part[4][4];
    #pragma unroll
    for (int i = 0; i < 4; ++i)
        #pragma unroll
        for (int j = 0; j < 4; ++j)
            #pragma unroll
            for (int r = 0; r < 4; ++r)
                part[i][j][r] = 65536.0f * (float)achh[i][j][r] +
                                  256.0f * (float)acx[i][j][r];

    // ---- phase 2: ll (lo planes only; L3-resident after phase 1) ----
    i32x4 acll[4][4];
    #pragma unroll
    for (int i = 0; i < 4; ++i)
        #pragma unroll
        for (int j = 0; j < 4; ++j) acll[i][j] = izero;

    for (int kt = 0; kt < nk; ++kt) {
        const long ko = (long)kt * 64;
        u32x4 sA0 = *(const u32x4*)(pAl + aoff0 + ko);
        u32x4 sA1 = *(const u32x4*)(pAl + aoff1 + ko);
        u32x4 sB0 = *(const u32x4*)(pBl + boff0 + ko);
        u32x4 sB1 = *(const u32x4*)(pBl + boff1 + ko);
        __syncthreads();
        *(u32x4*)&shA[0][sidx0] = sA0;
        *(u32x4*)&shA[0][sidx1] = sA1;
        *(u32x4*)&shB[0][sidx0] = sB0;
        *(u32x4*)&shB[0][sidx1] = sB1;
        __syncthreads();

        i32x4 fa[4];
        #pragma unroll
        for (int i = 0; i < 4; ++i)
            fa[i] = *(const i32x4*)&shA[0][(wm * 64 + i * 16 + l16) * LDT + kq * 16];
        #pragma unroll
        for (int j = 0; j < 4; ++j) {
            i32x4 fb = *(const i32x4*)&shB[0][(wn * 64 + j * 16 + l16) * LDT + kq * 16];
            #pragma unroll
            for (int i = 0; i < 4; ++i)
                acll[i][j] = __builtin_amdgcn_mfma_i32_16x16x64_i8(fa[i], fb, acll[i][j], 0, 0, 0);
        }
    }

    // epilogue: C/D layout col=lane&15, row=(lane>>4)*4+reg
    #pragma unroll
    for (int i = 0; i < 4; ++i) {
        const long gr0 = rowBase + wm * 64 + i * 16 + kq * 4;
        #pragma unroll
        for (int j = 0; j < 4; ++j) {
            const long gc = colBase + wn * 64 + j * 16 + l16;
            #pragma unroll
            for (int r = 0; r < 4; ++r) {
                const float comb = part[i][j][r] + (float)acll[i][j][r];
                const long o = (gr0 + r) * (long)N + gc;
                if constexpr (EPI == 0) {
                    i8 d1, d0;
                    digits256(comb, oscale, d1, d0);
                    Qh[o] = d1;
                    Ql[o] = d0;
                } else {
                    Cf[(long)z * strC + o] = comb * oscale;
                }
            }
        }
    }
}

// ---------------------------------------------------------------------------
// fp16 GEMM: C[M,N] = A[M,K] @ Bt[N,K]^T, single pass.
// EPI 2: fp16 transposed write (vT, batch-decomposed flat M=9216).
// EPI 3: fp32 + bias[col].
// ---------------------------------------------------------------------------
template <int EPI>
__global__ __launch_bounds__(256, 2) void gemm_f16(
    const u16* __restrict__ A, const u16* __restrict__ B,
    u16* __restrict__ Ch, float* __restrict__ Cf,
    const float* __restrict__ bias,
    int N, int K, long strA, long strB, long strC) {
    constexpr int LDT = 40;  // 32 + 8 pad (u16 elems)
    __shared__ u16 shA[128 * LDT];
    __shared__ u16 shB[128 * LDT];

    const int tid  = threadIdx.x;
    const int lane = tid & 63;
    const int wv   = tid >> 6;
    const int wm   = wv >> 1, wn = wv & 1;
    const int l16  = lane & 15, kq = lane >> 4;
    const int z    = blockIdx.z;
    int tx, ty;
    tile_swizzle(tx, ty);
    const long rowBase = (long)ty * 128;
    const long colBase = (long)tx * 128;

    const u16* pA = A + (long)z * strA;
    const u16* pB = B + (long)z * strB;

    const int r0 = tid >> 2;
    const int c0 = (tid & 3) * 8;
    const int r1 = r0 + 64;
    const long aoff0 = (rowBase + r0) * (long)K + c0;
    const long aoff1 = (rowBase + r1) * (long)K + c0;
    const long boff0 = (colBase + r0) * (long)K + c0;
    const long boff1 = (colBase + r1) * (long)K + c0;
    const int sidx0 = r0 * LDT + c0;
    const int sidx1 = r1 * LDT + c0;

    const f32x4 vzero = {0.f, 0.f, 0.f, 0.f};
    f32x4 acc[4][4];
    #pragma unroll
    for (int i = 0; i < 4; ++i)
        #pragma unroll
        for (int j = 0; j < 4; ++j) acc[i][j] = vzero;

    const int nk = K >> 5;
    for (int kt = 0; kt < nk; ++kt) {
        const long ko = (long)kt * 32;
        u32x4 sA0 = *(const u32x4*)(pA + aoff0 + ko);
        u32x4 sA1 = *(const u32x4*)(pA + aoff1 + ko);
        u32x4 sB0 = *(const u32x4*)(pB + boff0 + ko);
        u32x4 sB1 = *(const u32x4*)(pB + boff1 + ko);
        __syncthreads();
        *(u32x4*)&shA[sidx0] = sA0;
        *(u32x4*)&shA[sidx1] = sA1;
        *(u32x4*)&shB[sidx0] = sB0;
        *(u32x4*)&shB[sidx1] = sB1;
        __syncthreads();

        f16x8 fa[4];
        #pragma unroll
        for (int i = 0; i < 4; ++i) {
            const int off = (wm * 64 + i * 16 + l16) * LDT + kq * 8;
            fa[i] = __builtin_bit_cast(f16x8, *(const u32x4*)&shA[off]);
        }
        #pragma unroll
        for (int j = 0; j < 4; ++j) {
            const int off = (wn * 64 + j * 16 + l16) * LDT + kq * 8;
            f16x8 fb = __builtin_bit_cast(f16x8, *(const u32x4*)&shB[off]);
            #pragma unroll
            for (int i = 0; i < 4; ++i)
                acc[i][j] = __builtin_amdgcn_mfma_f32_16x16x32_f16(fa[i], fb, acc[i][j], 0, 0, 0);
        }
    }

    #pragma unroll
    for (int i = 0; i < 4; ++i) {
        const long gr0 = rowBase + wm * 64 + i * 16 + kq * 4;
        #pragma unroll
        for (int j = 0; j < 4; ++j) {
            const long gc = colBase + wn * 64 + j * 16 + l16;
            f32x4 a = acc[i][j];
            if constexpr (EPI == 2) {
                const int b  = (int)(gr0 / 2304);
                const int n0 = (int)(gr0 - (long)b * 2304);
                u16x4 o4;
                #pragma unroll
                for (int r = 0; r < 4; ++r) o4[r] = __builtin_bit_cast(u16, (f16)a[r]);
                *(u16x4*)&Ch[(long)b * (1024L * 2304) + gc * 2304 + n0] = o4;
            } else {
                float* C = Cf + (long)z * strC;
                const float bv = bias[gc];
                #pragma unroll
                for (int r = 0; r < 4; ++r) C[(gr0 + r) * (long)N + gc] = a[r] + bv;
            }
        }
    }
}

// ---------------------------------------------------------------------------
// Row softmax over 2304 cols with per-column bias c[m]; fp32 in, fp16 out.
// ---------------------------------------------------------------------------
__global__ __launch_bounds__(256) void softmax_k(const float* __restrict__ adj,
                                                 const float* __restrict__ c,
                                                 u16* __restrict__ P) {
    const int n = 2304;
    const int row = blockIdx.x, b = blockIdx.y;
    const int tid = threadIdx.x;
    const float* ar = adj + ((long)b * n + row) * (long)n;
    const float* cb = c + (long)b * n;
    u16* pr = P + ((long)b * n + row) * (long)n;

    float v[9];
    float mx = -3.0e38f;
    #pragma unroll
    for (int t = 0; t < 9; ++t) {
        const int i = t * 256 + tid;
        const float x = ar[i] + cb[i];
        v[t] = x;
        mx = fmaxf(mx, x);
    }
    #pragma unroll
    for (int off = 32; off >= 1; off >>= 1) mx = fmaxf(mx, __shfl_down(mx, off));
    __shared__ float red[4];
    if ((tid & 63) == 0) red[tid >> 6] = mx;
    __syncthreads();
    mx = fmaxf(fmaxf(red[0], red[1]), fmaxf(red[2], red[3]));

    float s = 0.f;
    #pragma unroll
    for (int t = 0; t < 9; ++t) {
        const float e = __expf(v[t] - mx);
        v[t] = e;
        s += e;
    }
    #pragma unroll
    for (int off = 32; off >= 1; off >>= 1) s += __shfl_down(s, off);
    __shared__ float red2[4];
    if ((tid & 63) == 0) red2[tid >> 6] = s;
    __syncthreads();
    s = red2[0] + red2[1] + red2[2] + red2[3];
    const float inv = 1.0f / s;
    #pragma unroll
    for (int t = 0; t < 9; ++t)
        pr[t * 256 + tid] = __builtin_bit_cast(u16, (f16)(v[t] * inv));
}

// ---------------------------------------------------------------------------
// Host launch
// ---------------------------------------------------------------------------
extern "C" void kernel_launch(void* const* d_in, const int* in_sizes, int n_in,
                              void* d_out, int out_size, void* d_ws, size_t ws_size,
                              hipStream_t stream) {
    (void)in_sizes; (void)n_in; (void)out_size; (void)ws_size;
    const float* F  = (const float*)d_in[0];  // [9216, 2048]
    const float* Wq = (const float*)d_in[1];  // [2048,2048]
    const float* bq = (const float*)d_in[2];  // [2048]
    const float* Wk = (const float*)d_in[3];  // [2048,2048]
    // d_in[4] (bk) drops out: row-constant under softmax.
    const float* Wu = (const float*)d_in[5];  // [2048,1024]
    const float* bu = (const float*)d_in[6];  // [1024]
    float* out = (float*)d_out;               // [9216, 1024]

    char* ws = (char*)d_ws;
    const long o_F16  = 0L;                      // 37748736
    const long o_Fh8  = 37748736L;               // 18874368
    const long o_Fl8  = 56623104L;
    const long o_Sh8  = 75497472L;
    const long o_Sl8  = 94371840L;
    const long o_adj  = 113246208L;              // 84934656
    const long o_P    = 198180864L;              // 42467328
    const long o_vT   = 240648192L;              // 18874368
    const long o_WuT  = 259522560L;              // 4194304
    const long o_Wqh  = 263716864L;
    const long o_Wql  = 267911168L;
    const long o_Wkh  = 272105472L;
    const long o_Wkl  = 276299776L;
    const long o_Mth  = 280494080L;
    const long o_Mtl  = 284688384L;
    const long o_u    = 288882688L;
    const long o_c    = 288890880L;

    u16* F16 = (u16*)(ws + o_F16);
    i8*  Fh8 = (i8*)(ws + o_Fh8);   i8* Fl8 = (i8*)(ws + o_Fl8);
    i8*  Sh8 = (i8*)(ws + o_Sh8);   i8* Sl8 = (i8*)(ws + o_Sl8);
    float* adj = (float*)(ws + o_adj);
    u16* P   = (u16*)(ws + o_P);
    u16* vT  = (u16*)(ws + o_vT);
    u16* WuT = (u16*)(ws + o_WuT);
    i8*  Wqh = (i8*)(ws + o_Wqh);   i8* Wql = (i8*)(ws + o_Wql);
    i8*  Wkh = (i8*)(ws + o_Wkh);   i8* Wkl = (i8*)(ws + o_Wkl);
    i8*  Mth = (i8*)(ws + o_Mth);   i8* Mtl = (i8*)(ws + o_Mtl);
    float* u = (float*)(ws + o_u);
    float* c = (float*)(ws + o_c);

    // --- pre-passes ---
    quantF_k<<<73728, 256, 0, stream>>>(F, F16, Fh8, Fl8, 18874368L);
    quantW_k<<<16384, 256, 0, stream>>>(Wq, Wqh, Wql, 4194304L);
    quantW_k<<<16384, 256, 0, stream>>>(Wk, Wkh, Wkl, 4194304L);
    wut_k<<<8192, 256, 0, stream>>>(Wu, WuT);
    gemv_k<<<2048, 256, 0, stream>>>(Wk, bq, u, 2048);   // u = Wk bq
    gemv_k<<<9216, 256, 0, stream>>>(F, u, c, 2048);     // c = F u

    // --- Mt = Wk @ Wq^T [2048x2048]; comb/s_W^2 requantized at s_Mt:
    //     r = comb * (s_Mt / s_W^2) = comb / 261120 ---
    gemm_i8<0><<<dim3(16, 16, 1), 256, 0, stream>>>(
        Wkh, Wkl, Wqh, Wql, Mth, Mtl, nullptr,
        3.8296569e-06f /* 1/261120 */, 2048, 2048, 0L, 0L, 0L);

    // --- S = F @ Mt^T [9216x2048]; r = comb * (s_S/(s_F*s_Mt)) = comb/261120 ---
    gemm_i8<0><<<dim3(16, 72, 1), 256, 0, stream>>>(
        Fh8, Fl8, Mth, Mtl, Sh8, Sl8, nullptr,
        3.8296569e-06f /* 1/261120 */, 2048, 2048, 0L, 0L, 0L);

    // --- adj = S @ F^T per batch [2304x2304]; val = comb / (5440^2) ---
    gemm_i8<1><<<dim3(18, 18, 4), 256, 0, stream>>>(
        Sh8, Sl8, Fh8, Fl8, nullptr, nullptr, adj,
        3.3791083e-08f /* 1/29593600 */, 2304, 2048,
        2304L * 2048, 2304L * 2048, 2304L * 2304);

    // --- P = softmax(adj + c), fp16 ---
    softmax_k<<<dim3(2304, 4, 1), 256, 0, stream>>>(adj, c, P);

    // --- v = F @ Wu (fp16), written transposed vT[b][1024][2304] ---
    gemm_f16<2><<<dim3(8, 72, 1), 256, 0, stream>>>(
        F16, WuT, vT, nullptr, nullptr, 1024, 2048, 0L, 0L, 0L);

    // --- out = P @ v + bu, fp32 ---
    gemm_f16<3><<<dim3(8, 18, 4), 256, 0, stream>>>(
        P, vT, nullptr, out, bu, 1024, 2304,
        2304L * 2304, 1024L * 2304, 2304L * 1024);
}

// Round 4
// 662.384 us; speedup vs baseline: 1.6197x; 1.3402x over previous
//
#include <hip/hip_runtime.h>

// ============================================================================
// GNN_22170621182157 R4: merged single-pass 4-term i8 K-loop (3 i32 acc sets)
// + global_load_lds(16B) staging + LDS double-buffer + raw s_barrier with
// manual s_waitcnt vmcnt(8) (prefetch stays in flight across the barrier).
//
// Math (softmax row-shift invariance):
//   softmax(adj) == softmax( S F^T + 1*c^T ), S = F Mt^T, Mt = Wk Wq^T,
//   c = F (Wk bq);  out = P (F Wu) + bu.
// Fixed-point: x ~ r/s, r = a1*256 + a0 (i8 digits).  s_F=s_S=5440,
// s_W=s_Mt=261120.  comb = 65536*hh + 256*(a1b0+a0b1) + a0b0 (all i32 exact).
// ============================================================================

typedef unsigned short u16;
typedef unsigned int   u32;
typedef signed char    i8;
typedef _Float16 f16;
typedef f16    f16x8 __attribute__((ext_vector_type(8)));
typedef float  f32x4 __attribute__((ext_vector_type(4)));
typedef int    i32x4 __attribute__((ext_vector_type(4)));
typedef u32    u32x4 __attribute__((ext_vector_type(4)));
typedef u16    u16x4 __attribute__((ext_vector_type(4)));

#define WAIT_VM8   0x0F78  // vmcnt(8),  exp 7, lgkm 15
#define WAIT_VM4   0x0F74  // vmcnt(4)
#define WAIT_VM0   0x0F70  // vmcnt(0)
#define WAIT_LGKM0 0xC07F  // lgkmcnt(0), vm 63, exp 7

__device__ __forceinline__ void gload16(const void* g, void* l) {
    __builtin_amdgcn_global_load_lds(
        (const __attribute__((address_space(1))) unsigned int*)g,
        (__attribute__((address_space(3))) unsigned int*)l, 16, 0, 0);
}

__device__ __forceinline__ void tile_swizzle(int& tx, int& ty) {
    const int gx = gridDim.x, gy = gridDim.y;
    const int lin = blockIdx.y * gx + blockIdx.x;
    const int G = 4;
    const int gid = lin / (G * gx);
    const int g0 = gid * G;
    const int gh = min(G, gy - g0);
    const int rem = lin - gid * (G * gx);
    ty = g0 + rem % gh;
    tx = rem / gh;
}

__device__ __forceinline__ void digits256(float v, float s, i8& d1, i8& d0) {
    float f = fminf(fmaxf(v * s, -32600.0f), 32600.0f);
    int r = __float2int_rn(f);
    int a1 = (r + 128) >> 8;
    int a0 = r - (a1 << 8);
    d1 = (i8)a1;
    d0 = (i8)a0;
}

// ---------------------------------------------------------------------------
// Pre-passes
// ---------------------------------------------------------------------------
// Fused: F fp32 -> fp16 + i8 digit planes (scale 5440) + c[row] = F[row].u
__global__ __launch_bounds__(256) void quantFc_k(const float* __restrict__ F,
                                                 const float* __restrict__ u,
                                                 u16* __restrict__ F16,
                                                 i8* __restrict__ hi,
                                                 i8* __restrict__ lo,
                                                 float* __restrict__ c) {
    const long row = blockIdx.x;
    const int tid = threadIdx.x;
    const float* fr = F + row * 2048;
    float dot = 0.f;
    #pragma unroll
    for (int t = 0; t < 8; ++t) {
        const int i = t * 256 + tid;
        const float v = fr[i];
        F16[row * 2048 + i] = __builtin_bit_cast(u16, (f16)v);
        i8 d1, d0;
        digits256(v, 5440.0f, d1, d0);
        hi[row * 2048 + i] = d1;
        lo[row * 2048 + i] = d0;
        dot += v * u[i];
    }
    #pragma unroll
    for (int off = 32; off >= 1; off >>= 1) dot += __shfl_down(dot, off);
    __shared__ float red[4];
    if ((tid & 63) == 0) red[tid >> 6] = dot;
    __syncthreads();
    if (tid == 0) c[row] = red[0] + red[1] + red[2] + red[3];
}

__global__ __launch_bounds__(256) void quantW_k(const float* __restrict__ x,
                                                i8* __restrict__ hi,
                                                i8* __restrict__ lo, long n) {
    long i = (long)blockIdx.x * 256 + threadIdx.x;
    if (i < n) {
        i8 d1, d0;
        digits256(x[i], 261120.0f, d1, d0);
        hi[i] = d1;
        lo[i] = d0;
    }
}

// Wu [2048][1024] -> WuT [1024][2048] fp16, tiled transpose (coalesced r/w)
__global__ __launch_bounds__(256) void wut_k(const float* __restrict__ Wu,
                                             u16* __restrict__ WuT) {
    __shared__ float t[32][33];
    const int bx = blockIdx.x * 32;  // col tile of Wu
    const int by = blockIdx.y * 32;  // row tile of Wu
    const int lx = threadIdx.x, ly = threadIdx.y;
    #pragma unroll
    for (int dy = 0; dy < 32; dy += 8)
        t[ly + dy][lx] = Wu[(long)(by + ly + dy) * 1024 + bx + lx];
    __syncthreads();
    #pragma unroll
    for (int dy = 0; dy < 32; dy += 8)
        WuT[(long)(bx + ly + dy) * 2048 + by + lx] =
            __builtin_bit_cast(u16, (f16)t[lx][ly + dy]);
}

// y[row] = A[row,:] . x  (fp32; used for u = Wk bq)
__global__ __launch_bounds__(256) void gemv_k(const float* __restrict__ A,
                                              const float* __restrict__ x,
                                              float* __restrict__ y, int ncols) {
    const long row = blockIdx.x;
    const float* ar = A + row * (long)ncols;
    float s = 0.f;
    for (int i = threadIdx.x; i < ncols; i += 256) s += ar[i] * x[i];
    #pragma unroll
    for (int off = 32; off >= 1; off >>= 1) s += __shfl_down(s, off);
    __shared__ float red[4];
    if ((threadIdx.x & 63) == 0) red[threadIdx.x >> 6] = s;
    __syncthreads();
    if (threadIdx.x == 0) y[row] = red[0] + red[1] + red[2] + red[3];
}

// ---------------------------------------------------------------------------
// i8 merged 4-term GEMM: C = A @ Bt^T.  128x128 tile, BK=64 B, 4 waves 2x2,
// wave 4x4 of mfma_i32_16x16x64_i8; acc sets hh/cross/ll.
// Staging: global_load_lds 16B into unpadded LDS (row=64B), chunk swizzle
// slot=(kq+(row>>1))&3 -> 2-way max bank alias on ds_read_b128 (free).
// Double-buffered; raw s_barrier + manual vmcnt(8): next-tile DMA in flight.
// EPI 0: requantize to digit planes.  EPI 1: fp32 out.
// ---------------------------------------------------------------------------
template <int EPI>
__global__ __launch_bounds__(256, 2) void gemm_i8(
    const i8* __restrict__ Ah, const i8* __restrict__ Al,
    const i8* __restrict__ Bh, const i8* __restrict__ Bl,
    i8* __restrict__ Qh, i8* __restrict__ Ql, float* __restrict__ Cf,
    float oscale, int N, int K, long strA, long strB, long strC) {
    // planes within one 32 KB buffer: Ah 0, Al 8K, Bh 16K, Bl 24K
    __shared__ __align__(16) i8 lds[2][32768];

    const int tid  = threadIdx.x;
    const int lane = tid & 63;
    const int wv   = tid >> 6;
    const int wm   = wv >> 1, wn = wv & 1;
    const int l16  = lane & 15, kq = lane >> 4;
    const int z    = blockIdx.z;
    int tx, ty;
    tile_swizzle(tx, ty);
    const long rowBase = (long)ty * 128;
    const long colBase = (long)tx * 128;

    const i8* pAh = Ah + (long)z * strA;
    const i8* pAl = Al + (long)z * strA;
    const i8* pBh = Bh + (long)z * strB;
    const i8* pBl = Bl + (long)z * strB;

    // ---- staging geometry (per wave: 2 row-halves per plane) ----
    const int l4r = lane >> 2, l4c = lane & 3;
    int rin[2], kqw[2];
    u32 voffA[2], voffB[2];
    int ldsoff[2];
    #pragma unroll
    for (int h = 0; h < 2; ++h) {
        rin[h] = h * 64 + wv * 16 + l4r;                 // row within tile
        kqw[h] = (l4c - (rin[h] >> 1)) & 3;              // global chunk this lane fetches
        voffA[h] = (u32)((rowBase + rin[h]) * (long)K) + kqw[h] * 16;
        voffB[h] = (u32)((colBase + rin[h]) * (long)K) + kqw[h] * 16;
        ldsoff[h] = (h * 64 + wv * 16) * 64;             // wave-uniform dest
    }

    // ---- fragment read offsets (chunk-swizzled) ----
    int aoff[4], boff[4];
    #pragma unroll
    for (int i = 0; i < 4; ++i) {
        const int rA = wm * 64 + i * 16 + l16;
        aoff[i] = rA * 64 + ((kq + (rA >> 1)) & 3) * 16;
        const int rB = wn * 64 + i * 16 + l16;
        boff[i] = rB * 64 + ((kq + (rB >> 1)) & 3) * 16;
    }

    const i32x4 izero = {0, 0, 0, 0};
    i32x4 ahh[4][4], acx[4][4], all_[4][4];
    #pragma unroll
    for (int i = 0; i < 4; ++i)
        #pragma unroll
        for (int j = 0; j < 4; ++j) { ahh[i][j] = izero; acx[i][j] = izero; all_[i][j] = izero; }

    const int nk = K >> 6;

    // issue tile 0 -> buf 0
    #pragma unroll
    for (int h = 0; h < 2; ++h) {
        gload16(pAh + voffA[h], &lds[0][0]     + ldsoff[h]);
        gload16(pAl + voffA[h], &lds[0][8192]  + ldsoff[h]);
        gload16(pBh + voffB[h], &lds[0][16384] + ldsoff[h]);
        gload16(pBl + voffB[h], &lds[0][24576] + ldsoff[h]);
    }

    for (int kt = 0; kt < nk; ++kt) {
        const int cur = kt & 1;
        if (kt + 1 < nk) {
            const long ko = (long)(kt + 1) * 64;
            i8* nb = lds[1 - cur];
            #pragma unroll
            for (int h = 0; h < 2; ++h) {
                gload16(pAh + voffA[h] + ko, nb         + ldsoff[h]);
                gload16(pAl + voffA[h] + ko, nb + 8192  + ldsoff[h]);
                gload16(pBh + voffB[h] + ko, nb + 16384 + ldsoff[h]);
                gload16(pBl + voffB[h] + ko, nb + 24576 + ldsoff[h]);
            }
            __builtin_amdgcn_s_waitcnt(WAIT_VM8);   // cur tile landed; next in flight
        } else {
            __builtin_amdgcn_s_waitcnt(WAIT_VM0);
        }
        __builtin_amdgcn_s_barrier();

        const i8* base = lds[cur];
        i32x4 fbh[4], fbl[4];
        #pragma unroll
        for (int j = 0; j < 4; ++j) {
            fbh[j] = *(const i32x4*)(base + 16384 + boff[j]);
            fbl[j] = *(const i32x4*)(base + 24576 + boff[j]);
        }
        #pragma unroll
        for (int i = 0; i < 4; ++i) {
            i32x4 fah = *(const i32x4*)(base + aoff[i]);
            i32x4 fal = *(const i32x4*)(base + 8192 + aoff[i]);
            #pragma unroll
            for (int j = 0; j < 4; ++j) {
                ahh[i][j]  = __builtin_amdgcn_mfma_i32_16x16x64_i8(fah, fbh[j], ahh[i][j], 0, 0, 0);
                acx[i][j]  = __builtin_amdgcn_mfma_i32_16x16x64_i8(fah, fbl[j], acx[i][j], 0, 0, 0);
                acx[i][j]  = __builtin_amdgcn_mfma_i32_16x16x64_i8(fal, fbh[j], acx[i][j], 0, 0, 0);
                all_[i][j] = __builtin_amdgcn_mfma_i32_16x16x64_i8(fal, fbl[j], all_[i][j], 0, 0, 0);
            }
        }
        __builtin_amdgcn_s_waitcnt(WAIT_LGKM0);     // my ds_reads done
        __builtin_amdgcn_s_barrier();               // buffer safe to overwrite
    }

    // epilogue: C/D layout col=lane&15, row=(lane>>4)*4+reg
    #pragma unroll
    for (int i = 0; i < 4; ++i) {
        const long gr0 = rowBase + wm * 64 + i * 16 + kq * 4;
        #pragma unroll
        for (int j = 0; j < 4; ++j) {
            const long gc = colBase + wn * 64 + j * 16 + l16;
            #pragma unroll
            for (int r = 0; r < 4; ++r) {
                const float comb = 65536.0f * (float)ahh[i][j][r] +
                                     256.0f * (float)acx[i][j][r] +
                                             (float)all_[i][j][r];
                const long o = (gr0 + r) * (long)N + gc;
                if constexpr (EPI == 0) {
                    i8 d1, d0;
                    digits256(comb, oscale, d1, d0);
                    Qh[o] = d1;
                    Ql[o] = d0;
                } else {
                    Cf[(long)z * strC + o] = comb * oscale;
                }
            }
        }
    }
}

// ---------------------------------------------------------------------------
// fp16 GEMM: C = A @ Bt^T, BK=32 (64 B rows — same staging geometry).
// global_load_lds + dbuf + raw barriers.  EPI 2: fp16 transposed write (vT);
// EPI 3: fp32 + bias[col].
// ---------------------------------------------------------------------------
template <int EPI>
__global__ __launch_bounds__(256, 3) void gemm_f16(
    const u16* __restrict__ A, const u16* __restrict__ B,
    u16* __restrict__ Ch, float* __restrict__ Cf,
    const float* __restrict__ bias,
    int N, int K, long strA, long strB, long strC) {
    // planes within one 16 KB buffer: A 0, B 8K
    __shared__ __align__(16) i8 lds[2][16384];

    const int tid  = threadIdx.x;
    const int lane = tid & 63;
    const int wv   = tid >> 6;
    const int wm   = wv >> 1, wn = wv & 1;
    const int l16  = lane & 15, kq = lane >> 4;
    const int z    = blockIdx.z;
    int tx, ty;
    tile_swizzle(tx, ty);
    const long rowBase = (long)ty * 128;
    const long colBase = (long)tx * 128;

    const u16* pA = A + (long)z * strA;
    const u16* pB = B + (long)z * strB;

    const int l4r = lane >> 2, l4c = lane & 3;
    u32 voffA[2], voffB[2];   // element (u16) units
    int ldsoff[2];            // byte units
    #pragma unroll
    for (int h = 0; h < 2; ++h) {
        const int rin = h * 64 + wv * 16 + l4r;
        const int kw = (l4c - (rin >> 1)) & 3;
        voffA[h] = (u32)((rowBase + rin) * (long)K) + kw * 8;
        voffB[h] = (u32)((colBase + rin) * (long)K) + kw * 8;
        ldsoff[h] = (h * 64 + wv * 16) * 64;
    }
    int aoff[4], boff[4];
    #pragma unroll
    for (int i = 0; i < 4; ++i) {
        const int rA = wm * 64 + i * 16 + l16;
        aoff[i] = rA * 64 + ((kq + (rA >> 1)) & 3) * 16;
        const int rB = wn * 64 + i * 16 + l16;
        boff[i] = rB * 64 + ((kq + (rB >> 1)) & 3) * 16;
    }

    const f32x4 vzero = {0.f, 0.f, 0.f, 0.f};
    f32x4 acc[4][4];
    #pragma unroll
    for (int i = 0; i < 4; ++i)
        #pragma unroll
        for (int j = 0; j < 4; ++j) acc[i][j] = vzero;

    const int nk = K >> 5;

    #pragma unroll
    for (int h = 0; h < 2; ++h) {
        gload16(pA + voffA[h], &lds[0][0]    + ldsoff[h]);
        gload16(pB + voffB[h], &lds[0][8192] + ldsoff[h]);
    }

    for (int kt = 0; kt < nk; ++kt) {
        const int cur = kt & 1;
        if (kt + 1 < nk) {
            const long ko = (long)(kt + 1) * 32;
            i8* nb = lds[1 - cur];
            #pragma unroll
            for (int h = 0; h < 2; ++h) {
                gload16(pA + voffA[h] + ko, nb        + ldsoff[h]);
                gload16(pB + voffB[h] + ko, nb + 8192 + ldsoff[h]);
            }
            __builtin_amdgcn_s_waitcnt(WAIT_VM4);
        } else {
            __builtin_amdgcn_s_waitcnt(WAIT_VM0);
        }
        __builtin_amdgcn_s_barrier();

        const i8* base = lds[cur];
        f16x8 fa[4];
        #pragma unroll
        for (int i = 0; i < 4; ++i)
            fa[i] = __builtin_bit_cast(f16x8, *(const u32x4*)(base + aoff[i]));
        #pragma unroll
        for (int j = 0; j < 4; ++j) {
            f16x8 fb = __builtin_bit_cast(f16x8, *(const u32x4*)(base + 8192 + boff[j]));
            #pragma unroll
            for (int i = 0; i < 4; ++i)
                acc[i][j] = __builtin_amdgcn_mfma_f32_16x16x32_f16(fa[i], fb, acc[i][j], 0, 0, 0);
        }
        __builtin_amdgcn_s_waitcnt(WAIT_LGKM0);
        __builtin_amdgcn_s_barrier();
    }

    #pragma unroll
    for (int i = 0; i < 4; ++i) {
        const long gr0 = rowBase + wm * 64 + i * 16 + kq * 4;
        #pragma unroll
        for (int j = 0; j < 4; ++j) {
            const long gc = colBase + wn * 64 + j * 16 + l16;
            f32x4 a = acc[i][j];
            if constexpr (EPI == 2) {
                const int b  = (int)(gr0 / 2304);
                const int n0 = (int)(gr0 - (long)b * 2304);
                u16x4 o4;
                #pragma unroll
                for (int r = 0; r < 4; ++r) o4[r] = __builtin_bit_cast(u16, (f16)a[r]);
                *(u16x4*)&Ch[(long)b * (1024L * 2304) + gc * 2304 + n0] = o4;
            } else {
                float* C = Cf + (long)z * strC;
                const float bv = bias[gc];
                #pragma unroll
                for (int r = 0; r < 4; ++r) C[(gr0 + r) * (long)N + gc] = a[r] + bv;
            }
        }
    }
}

// ---------------------------------------------------------------------------
// Row softmax over 2304 cols with per-column bias c[m]; fp32 in, fp16 out.
// ---------------------------------------------------------------------------
__global__ __launch_bounds__(256) void softmax_k(const float* __restrict__ adj,
                                                 const float* __restrict__ c,
                                                 u16* __restrict__ P) {
    const int n = 2304;
    const int row = blockIdx.x, b = blockIdx.y;
    const int tid = threadIdx.x;
    const float* ar = adj + ((long)b * n + row) * (long)n;
    const float* cb = c + (long)b * n;
    u16* pr = P + ((long)b * n + row) * (long)n;

    float v[9];
    float mx = -3.0e38f;
    #pragma unroll
    for (int t = 0; t < 9; ++t) {
        const int i = t * 256 + tid;
        const float x = ar[i] + cb[i];
        v[t] = x;
        mx = fmaxf(mx, x);
    }
    #pragma unroll
    for (int off = 32; off >= 1; off >>= 1) mx = fmaxf(mx, __shfl_down(mx, off));
    __shared__ float red[4];
    if ((tid & 63) == 0) red[tid >> 6] = mx;
    __syncthreads();
    mx = fmaxf(fmaxf(red[0], red[1]), fmaxf(red[2], red[3]));

    float s = 0.f;
    #pragma unroll
    for (int t = 0; t < 9; ++t) {
        const float e = __expf(v[t] - mx);
        v[t] = e;
        s += e;
    }
    #pragma unroll
    for (int off = 32; off >= 1; off >>= 1) s += __shfl_down(s, off);
    __shared__ float red2[4];
    if ((tid & 63) == 0) red2[tid >> 6] = s;
    __syncthreads();
    s = red2[0] + red2[1] + red2[2] + red2[3];
    const float inv = 1.0f / s;
    #pragma unroll
    for (int t = 0; t < 9; ++t)
        pr[t * 256 + tid] = __builtin_bit_cast(u16, (f16)(v[t] * inv));
}

// ---------------------------------------------------------------------------
// Host launch
// ---------------------------------------------------------------------------
extern "C" void kernel_launch(void* const* d_in, const int* in_sizes, int n_in,
                              void* d_out, int out_size, void* d_ws, size_t ws_size,
                              hipStream_t stream) {
    (void)in_sizes; (void)n_in; (void)out_size; (void)ws_size;
    const float* F  = (const float*)d_in[0];  // [9216, 2048]
    const float* Wq = (const float*)d_in[1];  // [2048,2048]
    const float* bq = (const float*)d_in[2];  // [2048]
    const float* Wk = (const float*)d_in[3];  // [2048,2048]
    // d_in[4] (bk) drops out: row-constant under softmax.
    const float* Wu = (const float*)d_in[5];  // [2048,1024]
    const float* bu = (const float*)d_in[6];  // [1024]
    float* out = (float*)d_out;               // [9216, 1024]

    char* ws = (char*)d_ws;
    const long o_F16  = 0L;                      // 37748736
    const long o_Fh8  = 37748736L;
    const long o_Fl8  = 56623104L;
    const long o_Sh8  = 75497472L;
    const long o_Sl8  = 94371840L;
    const long o_adj  = 113246208L;              // 84934656
    const long o_P    = 198180864L;              // 42467328
    const long o_vT   = 240648192L;
    const long o_WuT  = 259522560L;
    const long o_Wqh  = 263716864L;
    const long o_Wql  = 267911168L;
    const long o_Wkh  = 272105472L;
    const long o_Wkl  = 276299776L;
    const long o_Mth  = 280494080L;
    const long o_Mtl  = 284688384L;
    const long o_u    = 288882688L;
    const long o_c    = 288890880L;

    u16* F16 = (u16*)(ws + o_F16);
    i8*  Fh8 = (i8*)(ws + o_Fh8);   i8* Fl8 = (i8*)(ws + o_Fl8);
    i8*  Sh8 = (i8*)(ws + o_Sh8);   i8* Sl8 = (i8*)(ws + o_Sl8);
    float* adj = (float*)(ws + o_adj);
    u16* P   = (u16*)(ws + o_P);
    u16* vT  = (u16*)(ws + o_vT);
    u16* WuT = (u16*)(ws + o_WuT);
    i8*  Wqh = (i8*)(ws + o_Wqh);   i8* Wql = (i8*)(ws + o_Wql);
    i8*  Wkh = (i8*)(ws + o_Wkh);   i8* Wkl = (i8*)(ws + o_Wkl);
    i8*  Mth = (i8*)(ws + o_Mth);   i8* Mtl = (i8*)(ws + o_Mtl);
    float* u = (float*)(ws + o_u);
    float* c = (float*)(ws + o_c);

    // --- pre-passes ---
    gemv_k<<<2048, 256, 0, stream>>>(Wk, bq, u, 2048);          // u = Wk bq
    quantFc_k<<<9216, 256, 0, stream>>>(F, u, F16, Fh8, Fl8, c); // F planes + c
    quantW_k<<<16384, 256, 0, stream>>>(Wq, Wqh, Wql, 4194304L);
    quantW_k<<<16384, 256, 0, stream>>>(Wk, Wkh, Wkl, 4194304L);
    wut_k<<<dim3(32, 64, 1), dim3(32, 8, 1), 0, stream>>>(Wu, WuT);

    // --- Mt = Wk @ Wq^T [2048x2048]; requant r = comb / 261120 ---
    gemm_i8<0><<<dim3(16, 16, 1), 256, 0, stream>>>(
        Wkh, Wkl, Wqh, Wql, Mth, Mtl, nullptr,
        3.8296569e-06f, 2048, 2048, 0L, 0L, 0L);

    // --- S = F @ Mt^T [9216x2048]; requant r = comb / 261120 ---
    gemm_i8<0><<<dim3(16, 72, 1), 256, 0, stream>>>(
        Fh8, Fl8, Mth, Mtl, Sh8, Sl8, nullptr,
        3.8296569e-06f, 2048, 2048, 0L, 0L, 0L);

    // --- adj = S @ F^T per batch [2304x2304]; val = comb / 5440^2 ---
    gemm_i8<1><<<dim3(18, 18, 4), 256, 0, stream>>>(
        Sh8, Sl8, Fh8, Fl8, nullptr, nullptr, adj,
        3.3791083e-08f, 2304, 2048,
        2304L * 2048, 2304L * 2048, 2304L * 2304);

    // --- P = softmax(adj + c), fp16 ---
    softmax_k<<<dim3(2304, 4, 1), 256, 0, stream>>>(adj, c, P);

    // --- v = F @ Wu (fp16), written transposed vT[b][1024][2304] ---
    gemm_f16<2><<<dim3(8, 72, 1), 256, 0, stream>>>(
        F16, WuT, vT, nullptr, nullptr, 1024, 2048, 0L, 0L, 0L);

    // --- out = P @ v + bu, fp32 ---
    gemm_f16<3><<<dim3(8, 18, 4), 256, 0, stream>>>(
        P, vT, nullptr, out, bu, 1024, 2304,
        2304L * 2304, 1024L * 2304, 2304L * 1024);
}